// Round 4
// baseline (1339.012 us; speedup 1.0000x reference)
//
#include <hip/hip_runtime.h>

#define N_NODES 50000
#define N_EDGES 1600000
#define R_WAV 4
#define D 128
#define NB 391                 // ceil(50000/128) buckets of 128 rows
#define CHUNK 4096             // edges per hist/partition block
#define NPBLK ((N_EDGES + CHUNK - 1) / CHUNK)   // 391
#define MAXB 4800              // bucket capacity for LDS sort (mean 4092, sigma 64)
#define NPAD 50176             // rows padded to multiple of 512 (sliced layout)

typedef unsigned int u32;
typedef unsigned short u16;

// fp32 -> bf16 bits, round-to-nearest-even
static __device__ inline u16 f2bf(float f) {
    u32 u = __float_as_uint(f);
    u = (u + 0x7FFFu + ((u >> 16) & 1u)) >> 16;
    return (u16)u;
}
static __device__ inline float bf_lo(u32 u) { return __uint_as_float(u << 16); }
static __device__ inline float bf_hi(u32 u) { return __uint_as_float(u & 0xFFFF0000u); }

// ---------------- GEMM: h = x @ W, bf16 sliced output [8][NPAD][16] ----------
__global__ __launch_bounds__(128) void gemm_xw(const float* __restrict__ x,
                                               const float* __restrict__ W,
                                               u16* __restrict__ h) {
    __shared__ float xs[4 * 128];
    const int j = threadIdx.x;
    const int row0 = blockIdx.x * 4;
    for (int t = j; t < 512; t += 128) xs[t] = x[(size_t)row0 * D + t];
    __syncthreads();
    float a0 = 0.f, a1 = 0.f, a2 = 0.f, a3 = 0.f;
#pragma unroll 8
    for (int k = 0; k < 128; ++k) {
        const float w = W[k * D + j];
        a0 += xs[k] * w;
        a1 += xs[128 + k] * w;
        a2 += xs[256 + k] * w;
        a3 += xs[384 + k] * w;
    }
    const size_t base = (size_t)(j >> 4) * NPAD * 16 + (j & 15);
    h[base + (size_t)(row0 + 0) * 16] = f2bf(a0);
    h[base + (size_t)(row0 + 1) * 16] = f2bf(a1);
    h[base + (size_t)(row0 + 2) * 16] = f2bf(a2);
    h[base + (size_t)(row0 + 3) * 16] = f2bf(a3);
}

// ---------------- bucket histogram (LDS-privatized, 391 bins) ----------------
__global__ __launch_bounds__(256) void bucket_hist(const int* __restrict__ rows,
                                                   int* __restrict__ cnt) {
    __shared__ int lh[NB];
    const int tid = threadIdx.x;
    for (int i = tid; i < NB; i += 256) lh[i] = 0;
    __syncthreads();
    const int e0 = blockIdx.x * CHUNK;
    const int e1 = min(e0 + CHUNK, N_EDGES);
    for (int i = e0 + tid; i < e1; i += 256) atomicAdd(&lh[rows[i] >> 7], 1);
    __syncthreads();
    for (int i = tid; i < NB; i += 256) {
        const int c = lh[i];
        if (c) atomicAdd(&cnt[i], c);
    }
}

// ---------------- scan of 391 bucket counts (single block) ----------------
__global__ __launch_bounds__(512) void scan_buckets(const int* __restrict__ cnt,
                                                    int* __restrict__ bptr,
                                                    int* __restrict__ bcur) {
    __shared__ int sa[512], sb[512];
    const int tid = threadIdx.x;
    const int v = (tid < NB) ? cnt[tid] : 0;
    sa[tid] = v;
    int* cur = sa;
    int* nxt = sb;
    for (int d = 1; d < 512; d <<= 1) {
        __syncthreads();
        int t = cur[tid];
        if (tid >= d) t += cur[tid - d];
        nxt[tid] = t;
        int* tmp = cur; cur = nxt; nxt = tmp;
    }
    __syncthreads();
    const int excl = cur[tid] - v;
    if (tid <= NB) bptr[tid] = excl;
    if (tid < NB) bcur[tid] = excl;
}

// ---------------- partition: LDS counting-sort chunks into bucket runs -------
__global__ __launch_bounds__(256) void partition_kernel(const int* __restrict__ rows,
                                                        const int* __restrict__ cols,
                                                        const float* __restrict__ vals,
                                                        int* __restrict__ bcur,
                                                        int2* __restrict__ cv) {
    __shared__ int lh[NB], lptr[NB], lcur[NB], lbase[NB];
    __shared__ int sa[256], sb[256];
    __shared__ int2 st[CHUNK];
    const int tid = threadIdx.x;
    for (int i = tid; i < NB; i += 256) lh[i] = 0;
    __syncthreads();
    const int e0 = blockIdx.x * CHUNK;
    const int e1 = min(e0 + CHUNK, N_EDGES);
    const int cnt = e1 - e0;
    for (int i = e0 + tid; i < e1; i += 256) atomicAdd(&lh[rows[i] >> 7], 1);
    __syncthreads();
    const int p0 = (2 * tid < NB) ? lh[2 * tid] : 0;
    const int p1 = (2 * tid + 1 < NB) ? lh[2 * tid + 1] : 0;
    sa[tid] = p0 + p1;
    int* cur = sa;
    int* nxt = sb;
    for (int d = 1; d < 256; d <<= 1) {
        __syncthreads();
        int t = cur[tid];
        if (tid >= d) t += cur[tid - d];
        nxt[tid] = t;
        int* tmp = cur; cur = nxt; nxt = tmp;
    }
    __syncthreads();
    const int pe = cur[tid] - (p0 + p1);
    if (2 * tid < NB)     { lptr[2 * tid] = pe;           lcur[2 * tid] = pe; }
    if (2 * tid + 1 < NB) { lptr[2 * tid + 1] = pe + p0;  lcur[2 * tid + 1] = pe + p0; }
    __syncthreads();
    for (int i = e0 + tid; i < e1; i += 256) {
        const int row = rows[i];
        const int b = row >> 7;
        const int pos = atomicAdd(&lcur[b], 1);
        st[pos] = make_int2((int)(((u32)row << 16) | (u32)cols[i]), __float_as_int(vals[i]));
    }
    __syncthreads();
    for (int b = tid; b < NB; b += 256) {
        const int c = lh[b];
        int gb = 0;
        if (c) gb = atomicAdd(&bcur[b], c);
        lbase[b] = gb - lptr[b];
    }
    __syncthreads();
    for (int i = tid; i < cnt; i += 256) {
        const int2 e = st[i];
        const int b = (int)((u32)e.x >> 23);
        cv[lbase[b] + i] = e;
    }
}

// ------- per-bucket CSR: 128-bin counting sort, emit packed 4B edges ---------
// cv4 entry: {bf16(val) : hi16, col : lo16}
__global__ __launch_bounds__(256) void bucket_csr(const int* __restrict__ bptr,
                                                  const int2* __restrict__ cv,
                                                  u32* __restrict__ cv4,
                                                  int* __restrict__ row_ptr) {
    __shared__ int lh[128], lexcl[128], lcur[128];
    __shared__ u32 st[MAXB];
    const int b = blockIdx.x;
    const int s = bptr[b], e1 = bptr[b + 1];
    const int cnt = e1 - s;
    const int tid = threadIdx.x;
    if (tid < 128) lh[tid] = 0;
    __syncthreads();
    for (int i = s + tid; i < e1; i += 256)
        atomicAdd(&lh[((u32)cv[i].x >> 16) & 127u], 1);
    __syncthreads();
    if (tid < 64) {
        const int p0 = lh[2 * tid], p1 = lh[2 * tid + 1];
        int ssum = p0 + p1;
#pragma unroll
        for (int d = 1; d < 64; d <<= 1) {
            const int t = __shfl_up(ssum, d, 64);
            if (tid >= d) ssum += t;
        }
        const int pe = ssum - (p0 + p1);
        lexcl[2 * tid] = pe;          lcur[2 * tid] = pe;
        lexcl[2 * tid + 1] = pe + p0; lcur[2 * tid + 1] = pe + p0;
    }
    __syncthreads();
    for (int i = s + tid; i < e1; i += 256) {
        const int2 E = cv[i];
        const int lr = (int)(((u32)E.x >> 16) & 127u);
        const int pos = atomicAdd(&lcur[lr], 1);
        if (pos < MAXB)
            st[pos] = ((u32)f2bf(__int_as_float(E.y)) << 16) | ((u32)E.x & 0xFFFFu);
    }
    __syncthreads();
    const int wb = (cnt < MAXB) ? cnt : MAXB;
    for (int i = tid; i < wb; i += 256) cv4[s + i] = st[i];
    if (tid < 128) {
        const int row = (b << 7) + tid;
        if (row < N_NODES) row_ptr[row] = s + lexcl[tid];
    }
    if (b == 0 && tid == 0) row_ptr[N_NODES] = N_EDGES;
}

// ---------------- sliced SpMM pass 1: y = bf16( filt * (A @ h) ) -------------
// blockIdx%8 = feature slice (pinned to XCD by round-robin dispatch).
// 8 lanes/edge (u32 = 2 bf16 cols), 8 edges per gather instruction, 4 groups.
__global__ __launch_bounds__(256) void spmm1(const int* __restrict__ row_ptr,
                                             const u32* __restrict__ cvp,
                                             const u32* __restrict__ hsl,
                                             const float* __restrict__ filt_r,
                                             u32* __restrict__ ysl) {
    const int slice = blockIdx.x & 7;
    const int w = threadIdx.x >> 6;
    const int lane = threadIdx.x & 63;
    const int wid = (blockIdx.x >> 3) * 4 + w;
    const u32* hs = hsl + (size_t)slice * NPAD * 8;
    u32* ys = ysl + (size_t)slice * NPAD * 8;
    const int esub = lane >> 3;    // edge within group of 8
    const int cp = lane & 7;       // col-pair within slice
    for (int rr = 0; rr < 4; ++rr) {
        const int row = wid * 4 + rr;
        int e = row_ptr[row];
        const int end = row_ptr[row + 1];
        float a0x = 0.f, a0y = 0.f, a1x = 0.f, a1y = 0.f;
        float a2x = 0.f, a2y = 0.f, a3x = 0.f, a3y = 0.f;
        for (; e + 32 <= end; e += 32) {
            const u32 u0 = cvp[e + esub];
            const u32 u1 = cvp[e + 8 + esub];
            const u32 u2 = cvp[e + 16 + esub];
            const u32 u3 = cvp[e + 24 + esub];
            const u32 g0 = hs[((u0 & 0xFFFFu) << 3) + cp];
            const u32 g1 = hs[((u1 & 0xFFFFu) << 3) + cp];
            const u32 g2 = hs[((u2 & 0xFFFFu) << 3) + cp];
            const u32 g3 = hs[((u3 & 0xFFFFu) << 3) + cp];
            const float v0 = __uint_as_float(u0 & 0xFFFF0000u);
            const float v1 = __uint_as_float(u1 & 0xFFFF0000u);
            const float v2 = __uint_as_float(u2 & 0xFFFF0000u);
            const float v3 = __uint_as_float(u3 & 0xFFFF0000u);
            a0x += v0 * bf_lo(g0); a0y += v0 * bf_hi(g0);
            a1x += v1 * bf_lo(g1); a1y += v1 * bf_hi(g1);
            a2x += v2 * bf_lo(g2); a2y += v2 * bf_hi(g2);
            a3x += v3 * bf_lo(g3); a3y += v3 * bf_hi(g3);
        }
        for (; e < end; e += 8) {
            const u32 u0 = cvp[e + esub];
            const float v0 = (e + esub < end) ? __uint_as_float(u0 & 0xFFFF0000u) : 0.f;
            const u32 g0 = hs[((u0 & 0xFFFFu) << 3) + cp];
            a0x += v0 * bf_lo(g0); a0y += v0 * bf_hi(g0);
        }
        float ax = (a0x + a1x) + (a2x + a3x);
        float ay = (a0y + a1y) + (a2y + a3y);
        ax += __shfl_xor(ax, 8, 64);  ay += __shfl_xor(ay, 8, 64);
        ax += __shfl_xor(ax, 16, 64); ay += __shfl_xor(ay, 16, 64);
        ax += __shfl_xor(ax, 32, 64); ay += __shfl_xor(ay, 32, 64);
        const float f = filt_r[row];
        if (lane < 8)
            ys[(size_t)row * 8 + lane] = (u32)f2bf(f * ax) | ((u32)f2bf(f * ay) << 16);
    }
}

// ---------------- sliced SpMM pass 2: out (+)= A @ y  (fp32 out) -------------
template <bool FIRST>
__global__ __launch_bounds__(256) void spmm2(const int* __restrict__ row_ptr,
                                             const u32* __restrict__ cvp,
                                             const u32* __restrict__ ysl,
                                             const float* __restrict__ bias,
                                             float* __restrict__ out) {
    const int slice = blockIdx.x & 7;
    const int w = threadIdx.x >> 6;
    const int lane = threadIdx.x & 63;
    const int wid = (blockIdx.x >> 3) * 4 + w;
    const u32* ys = ysl + (size_t)slice * NPAD * 8;
    const int esub = lane >> 3;
    const int cp = lane & 7;
    const float bx = bias[slice * 16 + 2 * (lane & 7)];
    const float by = bias[slice * 16 + 2 * (lane & 7) + 1];
    for (int rr = 0; rr < 4; ++rr) {
        const int row = wid * 4 + rr;
        int e = row_ptr[row];
        const int end = row_ptr[row + 1];
        float a0x = 0.f, a0y = 0.f, a1x = 0.f, a1y = 0.f;
        float a2x = 0.f, a2y = 0.f, a3x = 0.f, a3y = 0.f;
        for (; e + 32 <= end; e += 32) {
            const u32 u0 = cvp[e + esub];
            const u32 u1 = cvp[e + 8 + esub];
            const u32 u2 = cvp[e + 16 + esub];
            const u32 u3 = cvp[e + 24 + esub];
            const u32 g0 = ys[((u0 & 0xFFFFu) << 3) + cp];
            const u32 g1 = ys[((u1 & 0xFFFFu) << 3) + cp];
            const u32 g2 = ys[((u2 & 0xFFFFu) << 3) + cp];
            const u32 g3 = ys[((u3 & 0xFFFFu) << 3) + cp];
            const float v0 = __uint_as_float(u0 & 0xFFFF0000u);
            const float v1 = __uint_as_float(u1 & 0xFFFF0000u);
            const float v2 = __uint_as_float(u2 & 0xFFFF0000u);
            const float v3 = __uint_as_float(u3 & 0xFFFF0000u);
            a0x += v0 * bf_lo(g0); a0y += v0 * bf_hi(g0);
            a1x += v1 * bf_lo(g1); a1y += v1 * bf_hi(g1);
            a2x += v2 * bf_lo(g2); a2y += v2 * bf_hi(g2);
            a3x += v3 * bf_lo(g3); a3y += v3 * bf_hi(g3);
        }
        for (; e < end; e += 8) {
            const u32 u0 = cvp[e + esub];
            const float v0 = (e + esub < end) ? __uint_as_float(u0 & 0xFFFF0000u) : 0.f;
            const u32 g0 = ys[((u0 & 0xFFFFu) << 3) + cp];
            a0x += v0 * bf_lo(g0); a0y += v0 * bf_hi(g0);
        }
        float ax = (a0x + a1x) + (a2x + a3x);
        float ay = (a0y + a1y) + (a2y + a3y);
        ax += __shfl_xor(ax, 8, 64);  ay += __shfl_xor(ay, 8, 64);
        ax += __shfl_xor(ax, 16, 64); ay += __shfl_xor(ay, 16, 64);
        ax += __shfl_xor(ax, 32, 64); ay += __shfl_xor(ay, 32, 64);
        if (lane < 8) {
            float* op = out + (size_t)row * D + slice * 16 + 2 * lane;
            if (FIRST) {
                *(float2*)op = make_float2(ax + bx, ay + by);
            } else {
                const float2 c = *(const float2*)op;
                *(float2*)op = make_float2(c.x + ax, c.y + ay);
            }
        }
    }
}

extern "C" void kernel_launch(void* const* d_in, const int* in_sizes, int n_in,
                              void* d_out, int out_size, void* d_ws, size_t ws_size,
                              hipStream_t stream) {
    const float* x    = (const float*)d_in[0];  // [N,128]
    const float* vals = (const float*)d_in[1];  // [R,E]
    const float* W    = (const float*)d_in[2];  // [128,128]
    const float* filt = (const float*)d_in[3];  // [R*N,1]
    const float* bias = (const float*)d_in[4];  // [128]
    const int*   rows = (const int*)d_in[5];    // [R,E]
    const int*   cols = (const int*)d_in[6];    // [R,E]
    float* out = (float*)d_out;                 // [N,128]

    // ws layout (order matters: padded-tail gathers from slice 7 may read up to
    // ~2.1 MB past their region start — must land in allocated ws, not OOB).
    char* ws = (char*)d_ws;
    u16*  h       = (u16*)(ws);                        // 12,845,056 B  [8][NPAD][16] bf16
    u32*  y2      = (u32*)(ws + 12845056);             // 12,845,056 B  [8][NPAD][8]  bf16x2
    int2* cv8     = (int2*)(ws + 25690112);            // 12,800,000 B
    u32*  cv4     = (u32*)(ws + 38490112);             //  6,400,512 B (+pad)
    int*  row_ptr = (int*)(ws + 44890624);             // (N+1)*4
    int*  cnt     = (int*)(ws + 45090816);             // NB
    int*  bptr    = (int*)(ws + 45092416);             // NB+1
    int*  bcur    = (int*)(ws + 45094016);             // NB

    gemm_xw<<<N_NODES / 4, 128, 0, stream>>>(x, W, h);

    for (int r = 0; r < R_WAV; ++r) {
        const int*   rows_r = rows + (size_t)r * N_EDGES;
        const int*   cols_r = cols + (size_t)r * N_EDGES;
        const float* vals_r = vals + (size_t)r * N_EDGES;
        const float* filt_r = filt + (size_t)r * N_NODES;

        hipMemsetAsync(cnt, 0, NB * sizeof(int), stream);
        bucket_hist<<<NPBLK, 256, 0, stream>>>(rows_r, cnt);
        scan_buckets<<<1, 512, 0, stream>>>(cnt, bptr, bcur);
        partition_kernel<<<NPBLK, 256, 0, stream>>>(rows_r, cols_r, vals_r, bcur, cv8);
        bucket_csr<<<NB, 256, 0, stream>>>(bptr, cv8, cv4, row_ptr);
        // grid: 8 slices x 3125 row-chunk blocks; slice = blockIdx % 8
        spmm1<<<25000, 256, 0, stream>>>(row_ptr, cv4, (const u32*)h, filt_r, y2);
        if (r == 0)
            spmm2<true><<<25000, 256, 0, stream>>>(row_ptr, cv4, y2, bias, out);
        else
            spmm2<false><<<25000, 256, 0, stream>>>(row_ptr, cv4, y2, bias, out);
    }
}

// Round 5
// 737.168 us; speedup vs baseline: 1.8164x; 1.8164x over previous
//
#include <hip/hip_runtime.h>

#define N_NODES 50000
#define N_EDGES 1600000
#define R_WAV 4
#define D 128
#define NB 391                 // ceil(50000/128) buckets of 128 rows
#define CHUNK 4096             // edges per hist/partition block
#define NPBLK ((N_EDGES + CHUNK - 1) / CHUNK)   // 391
#define MAXB 4800              // bucket capacity for LDS sort (mean 4092, sigma 64)

typedef unsigned int u32;
typedef unsigned short u16;

// fp32 -> bf16 bits, round-to-nearest-even
static __device__ inline u16 f2bf(float f) {
    u32 u = __float_as_uint(f);
    u = (u + 0x7FFFu + ((u >> 16) & 1u)) >> 16;
    return (u16)u;
}
static __device__ inline float bf_lo(u32 u) { return __uint_as_float(u << 16); }
static __device__ inline float bf_hi(u32 u) { return __uint_as_float(u & 0xFFFF0000u); }

// ---------------- GEMM: h = x @ W, bf16 row-major [N][128] -------------------
__global__ __launch_bounds__(128) void gemm_xw(const float* __restrict__ x,
                                               const float* __restrict__ W,
                                               u16* __restrict__ h) {
    __shared__ float xs[4 * 128];
    const int j = threadIdx.x;
    const int row0 = blockIdx.x * 4;
    for (int t = j; t < 512; t += 128) xs[t] = x[(size_t)row0 * D + t];
    __syncthreads();
    float a0 = 0.f, a1 = 0.f, a2 = 0.f, a3 = 0.f;
#pragma unroll 8
    for (int k = 0; k < 128; ++k) {
        const float w = W[k * D + j];
        a0 += xs[k] * w;
        a1 += xs[128 + k] * w;
        a2 += xs[256 + k] * w;
        a3 += xs[384 + k] * w;
    }
    h[(size_t)(row0 + 0) * D + j] = f2bf(a0);
    h[(size_t)(row0 + 1) * D + j] = f2bf(a1);
    h[(size_t)(row0 + 2) * D + j] = f2bf(a2);
    h[(size_t)(row0 + 3) * D + j] = f2bf(a3);
}

// ------------- batched bucket histogram: grid (NPBLK, R_WAV) -----------------
__global__ __launch_bounds__(256) void bucket_hist_all(const int* __restrict__ rows_all,
                                                       int* __restrict__ cnt4) {
    __shared__ int lh[NB];
    const int r = blockIdx.y;
    const int* rows = rows_all + (size_t)r * N_EDGES;
    int* cnt = cnt4 + r * NB;
    const int tid = threadIdx.x;
    for (int i = tid; i < NB; i += 256) lh[i] = 0;
    __syncthreads();
    const int e0 = blockIdx.x * CHUNK;
    const int e1 = min(e0 + CHUNK, N_EDGES);
    for (int i = e0 + tid; i < e1; i += 256) atomicAdd(&lh[rows[i] >> 7], 1);
    __syncthreads();
    for (int i = tid; i < NB; i += 256) {
        const int c = lh[i];
        if (c) atomicAdd(&cnt[i], c);
    }
}

// ------------- batched scan of bucket counts: grid R_WAV ---------------------
__global__ __launch_bounds__(512) void scan_buckets_all(const int* __restrict__ cnt4,
                                                        int* __restrict__ bptr4,
                                                        int* __restrict__ bcur4) {
    __shared__ int sa[512], sb[512];
    const int r = blockIdx.x;
    const int* cnt = cnt4 + r * NB;
    int* bptr = bptr4 + r * (NB + 1);
    int* bcur = bcur4 + r * NB;
    const int tid = threadIdx.x;
    const int v = (tid < NB) ? cnt[tid] : 0;
    sa[tid] = v;
    int* cur = sa;
    int* nxt = sb;
    for (int d = 1; d < 512; d <<= 1) {
        __syncthreads();
        int t = cur[tid];
        if (tid >= d) t += cur[tid - d];
        nxt[tid] = t;
        int* tmp = cur; cur = nxt; nxt = tmp;
    }
    __syncthreads();
    const int excl = cur[tid] - v;
    if (tid <= NB) bptr[tid] = excl;
    if (tid < NB) bcur[tid] = excl;
}

// ---------------- partition: LDS counting-sort chunks into bucket runs -------
__global__ __launch_bounds__(256) void partition_kernel(const int* __restrict__ rows,
                                                        const int* __restrict__ cols,
                                                        const float* __restrict__ vals,
                                                        int* __restrict__ bcur,
                                                        int2* __restrict__ cv) {
    __shared__ int lh[NB], lptr[NB], lcur[NB], lbase[NB];
    __shared__ int sa[256], sb[256];
    __shared__ int2 st[CHUNK];
    const int tid = threadIdx.x;
    for (int i = tid; i < NB; i += 256) lh[i] = 0;
    __syncthreads();
    const int e0 = blockIdx.x * CHUNK;
    const int e1 = min(e0 + CHUNK, N_EDGES);
    const int cnt = e1 - e0;
    for (int i = e0 + tid; i < e1; i += 256) atomicAdd(&lh[rows[i] >> 7], 1);
    __syncthreads();
    const int p0 = (2 * tid < NB) ? lh[2 * tid] : 0;
    const int p1 = (2 * tid + 1 < NB) ? lh[2 * tid + 1] : 0;
    sa[tid] = p0 + p1;
    int* cur = sa;
    int* nxt = sb;
    for (int d = 1; d < 256; d <<= 1) {
        __syncthreads();
        int t = cur[tid];
        if (tid >= d) t += cur[tid - d];
        nxt[tid] = t;
        int* tmp = cur; cur = nxt; nxt = tmp;
    }
    __syncthreads();
    const int pe = cur[tid] - (p0 + p1);
    if (2 * tid < NB)     { lptr[2 * tid] = pe;           lcur[2 * tid] = pe; }
    if (2 * tid + 1 < NB) { lptr[2 * tid + 1] = pe + p0;  lcur[2 * tid + 1] = pe + p0; }
    __syncthreads();
    for (int i = e0 + tid; i < e1; i += 256) {
        const int row = rows[i];
        const int b = row >> 7;
        const int pos = atomicAdd(&lcur[b], 1);
        st[pos] = make_int2((int)(((u32)row << 16) | (u32)cols[i]), __float_as_int(vals[i]));
    }
    __syncthreads();
    for (int b = tid; b < NB; b += 256) {
        const int c = lh[b];
        int gb = 0;
        if (c) gb = atomicAdd(&bcur[b], c);
        lbase[b] = gb - lptr[b];
    }
    __syncthreads();
    for (int i = tid; i < cnt; i += 256) {
        const int2 e = st[i];
        const int b = (int)((u32)e.x >> 23);
        cv[lbase[b] + i] = e;
    }
}

// ------- per-bucket CSR: 128-bin counting sort, emit packed 4B edges ---------
// cv4 entry: {bf16(val) : hi16, col : lo16}
__global__ __launch_bounds__(256) void bucket_csr(const int* __restrict__ bptr,
                                                  const int2* __restrict__ cv,
                                                  u32* __restrict__ cv4,
                                                  int* __restrict__ row_ptr) {
    __shared__ int lh[128], lexcl[128], lcur[128];
    __shared__ u32 st[MAXB];
    const int b = blockIdx.x;
    const int s = bptr[b], e1 = bptr[b + 1];
    const int cnt = e1 - s;
    const int tid = threadIdx.x;
    if (tid < 128) lh[tid] = 0;
    __syncthreads();
    for (int i = s + tid; i < e1; i += 256)
        atomicAdd(&lh[((u32)cv[i].x >> 16) & 127u], 1);
    __syncthreads();
    if (tid < 64) {
        const int p0 = lh[2 * tid], p1 = lh[2 * tid + 1];
        int ssum = p0 + p1;
#pragma unroll
        for (int d = 1; d < 64; d <<= 1) {
            const int t = __shfl_up(ssum, d, 64);
            if (tid >= d) ssum += t;
        }
        const int pe = ssum - (p0 + p1);
        lexcl[2 * tid] = pe;          lcur[2 * tid] = pe;
        lexcl[2 * tid + 1] = pe + p0; lcur[2 * tid + 1] = pe + p0;
    }
    __syncthreads();
    for (int i = s + tid; i < e1; i += 256) {
        const int2 E = cv[i];
        const int lr = (int)(((u32)E.x >> 16) & 127u);
        const int pos = atomicAdd(&lcur[lr], 1);
        if (pos < MAXB)
            st[pos] = ((u32)f2bf(__int_as_float(E.y)) << 16) | ((u32)E.x & 0xFFFFu);
    }
    __syncthreads();
    const int wb = (cnt < MAXB) ? cnt : MAXB;
    for (int i = tid; i < wb; i += 256) cv4[s + i] = st[i];
    if (tid < 128) {
        const int row = (b << 7) + tid;
        if (row < N_NODES) row_ptr[row] = s + lexcl[tid];
    }
    if (b == 0 && tid == 0) row_ptr[N_NODES] = N_EDGES;
}

// ---------------- SpMM pass 1: y = bf16( filt * (A @ h) ) --------------------
// One wave per row. 2 edges per gather instruction: lanes 0-31 edge k, lanes
// 32-63 edge k+1; lane owns cols 4l..4l+3 via uint2 (contiguous 256 B / edge).
// cv4 words are wave-uniform -> scalar loads.
__global__ __launch_bounds__(256) void spmm1(const int* __restrict__ row_ptr,
                                             const u32* __restrict__ cvp,
                                             const u32* __restrict__ h2,
                                             const float* __restrict__ filt_r,
                                             u32* __restrict__ y2) {
    const int row = __builtin_amdgcn_readfirstlane(blockIdx.x * 4 + (threadIdx.x >> 6));
    const int lane = threadIdx.x & 63;
    const int half = lane >> 5;
    const int l = lane & 31;
    int e = row_ptr[row];
    const int end = row_ptr[row + 1];
    float a0 = 0.f, a1 = 0.f, a2 = 0.f, a3 = 0.f;
    float b0 = 0.f, b1 = 0.f, b2 = 0.f, b3 = 0.f;
    for (; e + 8 <= end; e += 8) {
        const u32 c0 = cvp[e], c1 = cvp[e + 1], c2 = cvp[e + 2], c3 = cvp[e + 3];
        const u32 c4 = cvp[e + 4], c5 = cvp[e + 5], c6 = cvp[e + 6], c7 = cvp[e + 7];
        const u32 uA = half ? c1 : c0;
        const u32 uB = half ? c3 : c2;
        const u32 uC = half ? c5 : c4;
        const u32 uD = half ? c7 : c6;
        const uint2 gA = *(const uint2*)(h2 + (uA & 0xFFFFu) * 64 + 2 * l);
        const uint2 gB = *(const uint2*)(h2 + (uB & 0xFFFFu) * 64 + 2 * l);
        const uint2 gC = *(const uint2*)(h2 + (uC & 0xFFFFu) * 64 + 2 * l);
        const uint2 gD = *(const uint2*)(h2 + (uD & 0xFFFFu) * 64 + 2 * l);
        const float vA = __uint_as_float(uA & 0xFFFF0000u);
        const float vB = __uint_as_float(uB & 0xFFFF0000u);
        const float vC = __uint_as_float(uC & 0xFFFF0000u);
        const float vD = __uint_as_float(uD & 0xFFFF0000u);
        a0 += vA * bf_lo(gA.x); a1 += vA * bf_hi(gA.x);
        a2 += vA * bf_lo(gA.y); a3 += vA * bf_hi(gA.y);
        b0 += vB * bf_lo(gB.x); b1 += vB * bf_hi(gB.x);
        b2 += vB * bf_lo(gB.y); b3 += vB * bf_hi(gB.y);
        a0 += vC * bf_lo(gC.x); a1 += vC * bf_hi(gC.x);
        a2 += vC * bf_lo(gC.y); a3 += vC * bf_hi(gC.y);
        b0 += vD * bf_lo(gD.x); b1 += vD * bf_hi(gD.x);
        b2 += vD * bf_lo(gD.y); b3 += vD * bf_hi(gD.y);
    }
    for (; e < end; e += 2) {
        const u32 c0 = cvp[e];
        const u32 c1 = (e + 1 < end) ? cvp[e + 1] : 0u;
        const u32 uA = half ? c1 : c0;
        const uint2 gA = *(const uint2*)(h2 + (uA & 0xFFFFu) * 64 + 2 * l);
        const float vA = __uint_as_float(uA & 0xFFFF0000u);
        a0 += vA * bf_lo(gA.x); a1 += vA * bf_hi(gA.x);
        a2 += vA * bf_lo(gA.y); a3 += vA * bf_hi(gA.y);
    }
    a0 += b0; a1 += b1; a2 += b2; a3 += b3;
    a0 += __shfl_xor(a0, 32, 64);
    a1 += __shfl_xor(a1, 32, 64);
    a2 += __shfl_xor(a2, 32, 64);
    a3 += __shfl_xor(a3, 32, 64);
    const float f = filt_r[row];
    if (half == 0) {
        uint2 o;
        o.x = (u32)f2bf(f * a0) | ((u32)f2bf(f * a1) << 16);
        o.y = (u32)f2bf(f * a2) | ((u32)f2bf(f * a3) << 16);
        *(uint2*)(y2 + (size_t)row * 64 + 2 * l) = o;
    }
}

// ---------------- SpMM pass 2: out (+)= A @ y  (fp32 out) --------------------
template <bool FIRST>
__global__ __launch_bounds__(256) void spmm2(const int* __restrict__ row_ptr,
                                             const u32* __restrict__ cvp,
                                             const u32* __restrict__ y2,
                                             const float* __restrict__ bias,
                                             float* __restrict__ out) {
    const int row = __builtin_amdgcn_readfirstlane(blockIdx.x * 4 + (threadIdx.x >> 6));
    const int lane = threadIdx.x & 63;
    const int half = lane >> 5;
    const int l = lane & 31;
    int e = row_ptr[row];
    const int end = row_ptr[row + 1];
    float a0 = 0.f, a1 = 0.f, a2 = 0.f, a3 = 0.f;
    float b0 = 0.f, b1 = 0.f, b2 = 0.f, b3 = 0.f;
    for (; e + 8 <= end; e += 8) {
        const u32 c0 = cvp[e], c1 = cvp[e + 1], c2 = cvp[e + 2], c3 = cvp[e + 3];
        const u32 c4 = cvp[e + 4], c5 = cvp[e + 5], c6 = cvp[e + 6], c7 = cvp[e + 7];
        const u32 uA = half ? c1 : c0;
        const u32 uB = half ? c3 : c2;
        const u32 uC = half ? c5 : c4;
        const u32 uD = half ? c7 : c6;
        const uint2 gA = *(const uint2*)(y2 + (uA & 0xFFFFu) * 64 + 2 * l);
        const uint2 gB = *(const uint2*)(y2 + (uB & 0xFFFFu) * 64 + 2 * l);
        const uint2 gC = *(const uint2*)(y2 + (uC & 0xFFFFu) * 64 + 2 * l);
        const uint2 gD = *(const uint2*)(y2 + (uD & 0xFFFFu) * 64 + 2 * l);
        const float vA = __uint_as_float(uA & 0xFFFF0000u);
        const float vB = __uint_as_float(uB & 0xFFFF0000u);
        const float vC = __uint_as_float(uC & 0xFFFF0000u);
        const float vD = __uint_as_float(uD & 0xFFFF0000u);
        a0 += vA * bf_lo(gA.x); a1 += vA * bf_hi(gA.x);
        a2 += vA * bf_lo(gA.y); a3 += vA * bf_hi(gA.y);
        b0 += vB * bf_lo(gB.x); b1 += vB * bf_hi(gB.x);
        b2 += vB * bf_lo(gB.y); b3 += vB * bf_hi(gB.y);
        a0 += vC * bf_lo(gC.x); a1 += vC * bf_hi(gC.x);
        a2 += vC * bf_lo(gC.y); a3 += vC * bf_hi(gC.y);
        b0 += vD * bf_lo(gD.x); b1 += vD * bf_hi(gD.x);
        b2 += vD * bf_lo(gD.y); b3 += vD * bf_hi(gD.y);
    }
    for (; e < end; e += 2) {
        const u32 c0 = cvp[e];
        const u32 c1 = (e + 1 < end) ? cvp[e + 1] : 0u;
        const u32 uA = half ? c1 : c0;
        const uint2 gA = *(const uint2*)(y2 + (uA & 0xFFFFu) * 64 + 2 * l);
        const float vA = __uint_as_float(uA & 0xFFFF0000u);
        a0 += vA * bf_lo(gA.x); a1 += vA * bf_hi(gA.x);
        a2 += vA * bf_lo(gA.y); a3 += vA * bf_hi(gA.y);
    }
    a0 += b0; a1 += b1; a2 += b2; a3 += b3;
    a0 += __shfl_xor(a0, 32, 64);
    a1 += __shfl_xor(a1, 32, 64);
    a2 += __shfl_xor(a2, 32, 64);
    a3 += __shfl_xor(a3, 32, 64);
    if (half == 0) {
        float* op = out + (size_t)row * D + 4 * l;
        if (FIRST) {
            const float4 bb = *(const float4*)(bias + 4 * l);
            *(float4*)op = make_float4(a0 + bb.x, a1 + bb.y, a2 + bb.z, a3 + bb.w);
        } else {
            const float4 cc = *(const float4*)op;
            *(float4*)op = make_float4(cc.x + a0, cc.y + a1, cc.z + a2, cc.w + a3);
        }
    }
}

extern "C" void kernel_launch(void* const* d_in, const int* in_sizes, int n_in,
                              void* d_out, int out_size, void* d_ws, size_t ws_size,
                              hipStream_t stream) {
    const float* x    = (const float*)d_in[0];  // [N,128]
    const float* vals = (const float*)d_in[1];  // [R,E]
    const float* W    = (const float*)d_in[2];  // [128,128]
    const float* filt = (const float*)d_in[3];  // [R*N,1]
    const float* bias = (const float*)d_in[4];  // [128]
    const int*   rows = (const int*)d_in[5];    // [R,E]
    const int*   cols = (const int*)d_in[6];    // [R,E]
    float* out = (float*)d_out;                 // [N,128]

    char* ws = (char*)d_ws;
    u16*  h       = (u16*)(ws);                    // 12,800,000 B bf16 [N][128]
    u32*  y2      = (u32*)(ws + 12800000);         // 12,800,000 B bf16 [N][128]
    int2* cv8     = (int2*)(ws + 25600000);        // 12,800,000 B
    u32*  cv4     = (u32*)(ws + 38400000);         //  6,400,512 B
    int*  row_ptr = (int*)(ws + 44800512);         // 200,064 B
    int*  cnt4    = (int*)(ws + 45000576);         // 4*NB
    int*  bptr4   = (int*)(ws + 45006976);         // 4*(NB+1)
    int*  bcur4   = (int*)(ws + 45013376);         // 4*NB

    gemm_xw<<<N_NODES / 4, 128, 0, stream>>>(x, W, h);

    hipMemsetAsync(cnt4, 0, 4 * NB * sizeof(int), stream);
    bucket_hist_all<<<dim3(NPBLK, R_WAV), 256, 0, stream>>>(rows, cnt4);
    scan_buckets_all<<<R_WAV, 512, 0, stream>>>(cnt4, bptr4, bcur4);

    for (int r = 0; r < R_WAV; ++r) {
        const int*   rows_r = rows + (size_t)r * N_EDGES;
        const int*   cols_r = cols + (size_t)r * N_EDGES;
        const float* vals_r = vals + (size_t)r * N_EDGES;
        const float* filt_r = filt + (size_t)r * N_NODES;

        partition_kernel<<<NPBLK, 256, 0, stream>>>(rows_r, cols_r, vals_r,
                                                    bcur4 + r * NB, cv8);
        bucket_csr<<<NB, 256, 0, stream>>>(bptr4 + r * (NB + 1), cv8, cv4, row_ptr);
        spmm1<<<N_NODES / 4, 256, 0, stream>>>(row_ptr, cv4, (const u32*)h, filt_r, y2);
        if (r == 0)
            spmm2<true><<<N_NODES / 4, 256, 0, stream>>>(row_ptr, cv4, y2, bias, out);
        else
            spmm2<false><<<N_NODES / 4, 256, 0, stream>>>(row_ptr, cv4, y2, bias, out);
    }
}